// Round 5
// baseline (768.196 us; speedup 1.0000x reference)
//
#include <hip/hip_runtime.h>
#include <hip/hip_bf16.h>
#include <cstdint>

// MupCausalSelfAttention on MI355X (gfx950), bf16 MFMA pipeline.
// B=4, T=2048, C=2048, H=16, Dh=128. muP scale = 1/Dh = 1/128.
//
// ws layout (bf16 elems):
//   qkv  : [8192][6144]                 50,331,648 elems
//   vT   : [64 bh][128 d][2048 t]       16,777,216
//   xb/y : [8192][2048] (y overlays xb) 16,777,216
//   wqT  : [6144][2048]                 12,582,912
//   woT  : [2048][2048]                  4,194,304
//   total 100,663,296 elems = 201,326,592 bytes of d_ws.

using f32x4  = __attribute__((ext_vector_type(4))) float;
using u32x4  = __attribute__((ext_vector_type(4))) unsigned int;
using u16x8  = __attribute__((ext_vector_type(8))) unsigned short;
using u16x4  = __attribute__((ext_vector_type(4))) unsigned short;
using bf16x8 = __attribute__((ext_vector_type(8))) __bf16;

__device__ __forceinline__ unsigned short f2bf(float f) {
  unsigned int u = __builtin_bit_cast(unsigned int, f);
  u += 0x7fffu + ((u >> 16) & 1u);   // round-to-nearest-even
  return (unsigned short)(u >> 16);
}

// async 16B global->LDS DMA (dest is wave-uniform base + lane*16)
__device__ __forceinline__ void async_copy16(const unsigned short* g, unsigned short* l) {
  __builtin_amdgcn_global_load_lds(
      (const __attribute__((address_space(1))) unsigned int*)g,
      (__attribute__((address_space(3))) unsigned int*)l,
      16, 0, 0);
}

// ---------------- cast x fp32 -> bf16, 8 elems/thread ----------------
__global__ __launch_bounds__(256) void cast_x_kernel(const float* __restrict__ x,
                                                     unsigned short* __restrict__ xb) {
  const size_t i = (size_t)blockIdx.x * 256 + threadIdx.x;
  const float* p = x + i * 8;
  f32x4 a = *(const f32x4*)p;
  f32x4 b = *(const f32x4*)(p + 4);
  u16x8 o;
#pragma unroll
  for (int e = 0; e < 4; ++e) { o[e] = f2bf(a[e]); o[e + 4] = f2bf(b[e]); }
  *(u32x4*)(xb + i * 8) = __builtin_bit_cast(u32x4, o);
}

// ---------- W[K][N] fp32 -> WT[N][K] bf16, 64x64 LDS tile ----------
__global__ __launch_bounds__(256) void transpose_cast_w(const float* __restrict__ W,
                                                        unsigned short* __restrict__ WT,
                                                        int K, int N) {
  __shared__ unsigned short tbuf[64 * 68];
  const int tid = threadIdx.x;
  const int k0 = blockIdx.x * 64, n0 = blockIdx.y * 64;
#pragma unroll
  for (int it = 0; it < 4; ++it) {
    int c = it * 256 + tid;
    int kl = c >> 4, n4 = (c & 15) * 4;
    f32x4 v = *(const f32x4*)(W + (size_t)(k0 + kl) * N + n0 + n4);
#pragma unroll
    for (int e = 0; e < 4; ++e) tbuf[(n4 + e) * 68 + kl] = f2bf(v[e]);
  }
  __syncthreads();
#pragma unroll
  for (int it = 0; it < 2; ++it) {
    int c = it * 256 + tid;
    int nl = c >> 3, k8 = (c & 7) * 8;
    u16x4 lo = *(const u16x4*)&tbuf[nl * 68 + k8];
    u16x4 hi = *(const u16x4*)&tbuf[nl * 68 + k8 + 4];
    u16x8 o;
#pragma unroll
    for (int e = 0; e < 4; ++e) { o[e] = lo[e]; o[e + 4] = hi[e]; }
    *(u32x4*)(WT + (size_t)(n0 + nl) * K + k0 + k8) = __builtin_bit_cast(u32x4, o);
  }
}

// ---- qkv V-slice -> vT[bh][128 d][2048 t] bf16, 64x64 LDS tile ----
__global__ __launch_bounds__(256) void transpose_v_kernel(const unsigned short* __restrict__ qkv,
                                                          unsigned short* __restrict__ vT) {
  __shared__ unsigned short tbuf[64 * 68];
  const int tid = threadIdx.x;
  const int t0 = blockIdx.x * 64;
  const int d0 = blockIdx.y * 64;
  const int bh = blockIdx.z;
  const int b = bh >> 4, h = bh & 15;
#pragma unroll
  for (int it = 0; it < 2; ++it) {
    int c = it * 256 + tid;
    int tl = c >> 3, d8 = (c & 7) * 8;
    u32x4 v = *(const u32x4*)(qkv + (size_t)(b * 2048 + t0 + tl) * 6144 + 4096 + h * 128 + d0 + d8);
    u16x8 u = __builtin_bit_cast(u16x8, v);
#pragma unroll
    for (int e = 0; e < 8; ++e) tbuf[(d8 + e) * 68 + tl] = u[e];
  }
  __syncthreads();
#pragma unroll
  for (int it = 0; it < 2; ++it) {
    int c = it * 256 + tid;
    int dl = c >> 3, t8 = (c & 7) * 8;
    u16x4 lo = *(const u16x4*)&tbuf[dl * 68 + t8];
    u16x4 hi = *(const u16x4*)&tbuf[dl * 68 + t8 + 4];
    u16x8 o;
#pragma unroll
    for (int e = 0; e < 4; ++e) { o[e] = lo[e]; o[e + 4] = hi[e]; }
    *(u32x4*)(vT + ((size_t)bh * 128 + d0 + dl) * 2048 + t0 + t8) = __builtin_bit_cast(u32x4, o);
  }
}

// ================== 256x256 8-phase GEMM (m201 geometry) ==================
// C[M,N] = A[M,K] @ BT[N,K]^T + bias. bf16 MFMA 16x16x32, BK=64.
// 512 threads = 8 waves (2M x 4N), per-wave C = 128x64.
// LDS per operand: [2 buf][2 row-half][128 rows][64 k] bf16 = 64KB; 128KB total.
// Row layout: 128B/row = 8 chunks of 16B; swizzle chunk c ^= (row&7) on BOTH
// staging source and fragment read (involution; 2 lanes/bank-group = free).
// Tile t lives in buf t&1. Tile t+2 overwrites the SAME buf region-by-region
// after each region's last read: B-halves (last read P2) staged at P3,
// A-halves (last read P3) staged at P4. ONE wait per K-tile: vmcnt(8) at
// P4-end. Issue-to-wait distance ~4-5 phases.

// stage one 16KB region (128 rows x 64 k bf16): 2 global_load_lds/thread
__device__ __forceinline__ void stage_region(const unsigned short* gsrc, int K,
                                             unsigned short* region, int tid) {
#pragma unroll
  for (int l = 0; l < 2; ++l) {
    const int s = l * 512 + tid;          // 0..1023 slots of 16B
    const int row = s >> 3, c = s & 7;
    const int g = c ^ (row & 7);
    async_copy16(gsrc + (size_t)row * K + g * 8, region + s * 8);
  }
}

__device__ __forceinline__ bf16x8 lds_frag(const unsigned short* region, int row, int ch) {
  return __builtin_bit_cast(bf16x8,
      *(const u32x4*)(region + row * 64 + ((ch ^ (row & 7)) * 8)));
}

template <bool OUT_BF16>
__global__ __launch_bounds__(512, 1) void gemm_bt(const unsigned short* __restrict__ A,
                                                  const unsigned short* __restrict__ BT,
                                                  const float* __restrict__ bias,
                                                  void* __restrict__ Cout,
                                                  int M, int N, int K) {
  __shared__ unsigned short As[32768];   // [buf][rh][128*64]
  __shared__ unsigned short Bs[32768];

  const int tid  = threadIdx.x;
  const int lane = tid & 63;
  const int wave = tid >> 6;
  const int r16  = lane & 15;
  const int quad = lane >> 4;
  const int wm   = (wave >> 2) * 128;
  const int wn   = (wave & 3) * 64;
  const int rhA  = wave >> 2;          // wave's A row-half
  const int rhB  = (wave >> 1) & 1;    // wave's B row-half
  const int brow = wn & 64;            // wave's base row within its B region

  // XCD-aware mapping: XCD x owns m-chunk [x*MC, x*MC+MC) x all n (n-major walk).
  const int orig = blockIdx.y * gridDim.x + blockIdx.x;
  const int xcd  = orig & 7;
  const int kb   = orig >> 3;
  const int MC   = gridDim.x >> 3;
  const int m0   = (xcd * MC + (kb % MC)) * 256;
  const int n0   = (kb / MC) * 256;

  const unsigned short* Ag = A + (size_t)m0 * K;
  const unsigned short* Bg = BT + (size_t)n0 * K;
  const int NT = K >> 6;

  f32x4 acc[8][4] = {};

  // prologue: stage tiles 0 and 1 in steady-state region order (B0,B1,A0,A1)
#pragma unroll
  for (int tt = 0; tt < 2; ++tt) {
    const size_t kk0 = (size_t)tt * 64;
    unsigned short* Ad = As + tt * 16384;
    unsigned short* Bd = Bs + tt * 16384;
    stage_region(Bg + kk0, K, Bd, tid);
    stage_region(Bg + (size_t)128 * K + kk0, K, Bd + 8192, tid);
    stage_region(Ag + kk0, K, Ad, tid);
    stage_region(Ag + (size_t)128 * K + kk0, K, Ad + 8192, tid);
  }
  asm volatile("s_waitcnt vmcnt(8)" ::: "memory");   // tile 0 landed; tile 1 in flight
  __builtin_amdgcn_s_barrier();

  for (int t = 0; t < NT; ++t) {
    const int buf = t & 1;
    const unsigned short* Ar = As + buf * 16384 + rhA * 8192;
    const unsigned short* Br = Bs + buf * 16384 + rhB * 8192;
    unsigned short* Asg = As + buf * 16384;   // tile t+2 overwrites current buf
    unsigned short* Bsg = Bs + buf * 16384;
    const bool pre = (t + 2 < NT);
    const size_t kpre = (size_t)(t + 2) << 6;

    bf16x8 a0[4][2], a1[4][2], b0[2][2], b1[2][2];

    // ---------------- P1: read A[mq0] + B[nq0]; MFMA acc[0-3][0-1] ----------------
#pragma unroll
    for (int mi = 0; mi < 4; ++mi)
#pragma unroll
      for (int kk = 0; kk < 2; ++kk)
        a0[mi][kk] = lds_frag(Ar, mi * 16 + r16, kk * 4 + quad);
#pragma unroll
    for (int nj = 0; nj < 2; ++nj)
#pragma unroll
      for (int kk = 0; kk < 2; ++kk)
        b0[nj][kk] = lds_frag(Br, brow + nj * 16 + r16, kk * 4 + quad);
    __builtin_amdgcn_s_barrier();
    asm volatile("s_waitcnt lgkmcnt(0)" ::: "memory");
    __builtin_amdgcn_sched_barrier(0);
    __builtin_amdgcn_s_setprio(1);
#pragma unroll
    for (int mi = 0; mi < 4; ++mi)
#pragma unroll
      for (int nj = 0; nj < 2; ++nj)
#pragma unroll
        for (int kk = 0; kk < 2; ++kk)
          acc[mi][nj] = __builtin_amdgcn_mfma_f32_16x16x32_bf16(a0[mi][kk], b0[nj][kk], acc[mi][nj], 0, 0, 0);
    __builtin_amdgcn_s_setprio(0);
    __builtin_amdgcn_s_barrier();

    // ---------------- P2: read B[nq1]; MFMA acc[0-3][2-3] ----------------
#pragma unroll
    for (int nj = 0; nj < 2; ++nj)
#pragma unroll
      for (int kk = 0; kk < 2; ++kk)
        b1[nj][kk] = lds_frag(Br, brow + 32 + nj * 16 + r16, kk * 4 + quad);
    __builtin_amdgcn_s_barrier();
    asm volatile("s_waitcnt lgkmcnt(0)" ::: "memory");
    __builtin_amdgcn_sched_barrier(0);
    __builtin_amdgcn_s_setprio(1);
#pragma unroll
    for (int mi = 0; mi < 4; ++mi)
#pragma unroll
      for (int nj = 0; nj < 2; ++nj)
#pragma unroll
        for (int kk = 0; kk < 2; ++kk)
          acc[mi][nj + 2] = __builtin_amdgcn_mfma_f32_16x16x32_bf16(a0[mi][kk], b1[nj][kk], acc[mi][nj + 2], 0, 0, 0);
    __builtin_amdgcn_s_setprio(0);
    __builtin_amdgcn_s_barrier();

    // ------- P3: read A[mq1]; stage B(t+2) both halves; MFMA acc[4-7][2-3] -------
#pragma unroll
    for (int mi = 0; mi < 4; ++mi)
#pragma unroll
      for (int kk = 0; kk < 2; ++kk)
        a1[mi][kk] = lds_frag(Ar, 64 + mi * 16 + r16, kk * 4 + quad);
    if (pre) {
      stage_region(Bg + kpre, K, Bsg, tid);
      stage_region(Bg + (size_t)128 * K + kpre, K, Bsg + 8192, tid);
    }
    __builtin_amdgcn_s_barrier();
    asm volatile("s_waitcnt lgkmcnt(0)" ::: "memory");
    __builtin_amdgcn_sched_barrier(0);
    __builtin_amdgcn_s_setprio(1);
#pragma unroll
    for (int mi = 0; mi < 4; ++mi)
#pragma unroll
      for (int nj = 0; nj < 2; ++nj)
#pragma unroll
        for (int kk = 0; kk < 2; ++kk)
          acc[mi + 4][nj + 2] = __builtin_amdgcn_mfma_f32_16x16x32_bf16(a1[mi][kk], b1[nj][kk], acc[mi + 4][nj + 2], 0, 0, 0);
    __builtin_amdgcn_s_setprio(0);
    __builtin_amdgcn_s_barrier();

    // ------- P4: stage A(t+2) both halves; MFMA acc[4-7][0-1]; vmcnt(8) -------
    if (pre) {
      stage_region(Ag + kpre, K, Asg, tid);
      stage_region(Ag + (size_t)128 * K + kpre, K, Asg + 8192, tid);
    }
    __builtin_amdgcn_s_barrier();
    __builtin_amdgcn_sched_barrier(0);
    __builtin_amdgcn_s_setprio(1);
#pragma unroll
    for (int mi = 0; mi < 4; ++mi)
#pragma unroll
      for (int nj = 0; nj < 2; ++nj)
#pragma unroll
        for (int kk = 0; kk < 2; ++kk)
          acc[mi + 4][nj] = __builtin_amdgcn_mfma_f32_16x16x32_bf16(a1[mi][kk], b0[nj][kk], acc[mi + 4][nj], 0, 0, 0);
    __builtin_amdgcn_s_setprio(0);
    if (pre) { asm volatile("s_waitcnt vmcnt(8)" ::: "memory"); }  // t+1 landed; t+2 flying
    else     { asm volatile("s_waitcnt vmcnt(0)" ::: "memory"); }
    __builtin_amdgcn_s_barrier();
  }

  // epilogue
#pragma unroll
  for (int nj = 0; nj < 4; ++nj) {
    const int n = n0 + wn + nj * 16 + r16;
    const float bv = bias[n];
#pragma unroll
    for (int mi = 0; mi < 8; ++mi) {
      const int mr = m0 + wm + mi * 16 + quad * 4;
#pragma unroll
      for (int r = 0; r < 4; ++r) {
        float v = acc[mi][nj][r] + bv;
        if constexpr (OUT_BF16)
          ((unsigned short*)Cout)[(size_t)(mr + r) * N + n] = f2bf(v);
        else
          ((float*)Cout)[(size_t)(mr + r) * N + n] = v;
      }
    }
  }
}

// --------------- flash attention v2, causal, muP scale 1/128 ---------------
// Block = 4 waves, 128 q-rows (32/wave as 2 m-tiles). kv tiles of 64.
// T14 async-STAGE: K/V tile t+1 loaded global->reg BEFORE computing tile t
// (issue-to-use distance = one compute phase >> HBM latency), then after the
// end-of-compute barrier: vmcnt(0) (free) -> ds_write -> lgkmcnt(0) -> issue
// loads t+2 -> barrier -> compute. Raw barriers; no vmcnt(0)-drain per tile.
// Grid (64 bh, 16 y): qt = 15-y so heavy blocks dispatch FIRST (no late tail);
// orig&7 = bh&7 so a head's K/V stays on one XCD's L2.
// No online max: muP scale 1/128 keeps logits O(1); softmax shift-invariant.
__global__ __launch_bounds__(256, 3) void attn_kernel(const unsigned short* __restrict__ qkv,
                                                      const unsigned short* __restrict__ vT,
                                                      unsigned short* __restrict__ y) {
  __shared__ unsigned short Ks[64 * 128];    // [kvrow][chunk c]: holds K chunk c^(row&15)
  __shared__ unsigned short Vs[128 * 64];    // [drow][chunk c]: holds vT chunk c^(drow&7)
  __shared__ unsigned short Ps[4][32 * 72];  // per-wave P (C-layout -> A-layout bridge)

  const int tid  = threadIdx.x;
  const int lane = tid & 63;
  const int wave = tid >> 6;
  const int r16  = lane & 15;
  const int quad = lane >> 4;
  const int qt   = 15 - blockIdx.y;          // heavy (large-q) blocks dispatch first
  const int q0   = qt * 128;
  const int bh   = blockIdx.x;               // XCD = bh&7 -> per-head L2 locality
  const int b    = bh >> 4, h = bh & 15;
  const int wq0  = q0 + wave * 32;
  unsigned short* pl = Ps[wave];

  // Q A-frags: Q[m=r16][k=kc*32+quad*8+j]
  bf16x8 aq[2][4];
#pragma unroll
  for (int mi = 0; mi < 2; ++mi) {
    const unsigned short* qp = qkv + (size_t)(b * 2048 + wq0 + mi * 16 + r16) * 6144 + h * 128;
#pragma unroll
    for (int kc = 0; kc < 4; ++kc)
      aq[mi][kc] = __builtin_bit_cast(bf16x8, *(const u32x4*)(qp + kc * 32 + quad * 8));
  }

  f32x4 o[2][8] = {};
  float rs_l[2][4] = {};

  const unsigned short* kbase = qkv + (size_t)b * 2048 * 6144 + 2048 + h * 128;
  const unsigned short* vbase = vT + (size_t)bh * 128 * 2048;
  const int ntiles = 2 * qt + 2;

  // staging geometry (swizzle applied on the GLOBAL side; LDS dest linear):
  // K: slot=it*256+tid -> row=it*16+(tid>>4), src chunk kg=(tid&15)^(tid>>4)
  // V: slot=it*256+tid -> dr=it*32+(tid>>3), src chunk vg=(tid&7)^((tid>>3)&7)
  const int kg = (tid & 15) ^ (tid >> 4);
  const int vg = (tid & 7) ^ ((tid >> 3) & 7);
  const int krow0 = tid >> 4;
  const int vrow0 = tid >> 3;

  u32x4 kreg[4], vreg[4];

#define ATTN_LOADREGS(KV0)                                                              \
  {                                                                                     \
    _Pragma("unroll")                                                                   \
    for (int it = 0; it < 4; ++it)                                                      \
      kreg[it] = *(const u32x4*)(kbase + (size_t)((KV0) + it * 16 + krow0) * 6144 + kg * 8); \
    _Pragma("unroll")                                                                   \
    for (int it = 0; it < 4; ++it)                                                      \
      vreg[it] = *(const u32x4*)(vbase + (size_t)(it * 32 + vrow0) * 2048 + (KV0) + vg * 8); \
  }

  ATTN_LOADREGS(0);

  for (int t = 0; t < ntiles; ++t) {
    const int kv0 = t * 64;
    // ---- stage phase: regs (loaded one compute-phase ago) -> LDS ----
    asm volatile("s_waitcnt vmcnt(0)" ::: "memory");   // near-free: issued ~1 tile ago
    __builtin_amdgcn_s_barrier();                      // prev compute done reading LDS
    __builtin_amdgcn_sched_barrier(0);
#pragma unroll
    for (int it = 0; it < 4; ++it)
      *(u32x4*)(Ks + (it * 256 + tid) * 8) = kreg[it];
#pragma unroll
    for (int it = 0; it < 4; ++it)
      *(u32x4*)(Vs + (it * 256 + tid) * 8) = vreg[it];
    asm volatile("s_waitcnt lgkmcnt(0)" ::: "memory"); // writes done; regs reusable
    if (t + 1 < ntiles) ATTN_LOADREGS(kv0 + 64);       // prefetch next tile
    __builtin_amdgcn_s_barrier();                      // all waves' writes visible
    __builtin_amdgcn_sched_barrier(0);

    // S = Q K^T  (B-frag: K[kv=n][d=k], swizzled read from Ks)
    f32x4 s[2][4] = {};
#pragma unroll
    for (int kc = 0; kc < 4; ++kc) {
#pragma unroll
      for (int nt = 0; nt < 4; ++nt) {
        const int krow = nt * 16 + r16;
        const int chunk = kc * 4 + quad;
        bf16x8 bk = __builtin_bit_cast(bf16x8,
            *(const u32x4*)(Ks + (krow * 16 + (chunk ^ (krow & 15))) * 8));
#pragma unroll
        for (int mi = 0; mi < 2; ++mi)
          s[mi][nt] = __builtin_amdgcn_mfma_f32_16x16x32_bf16(aq[mi][kc], bk, s[mi][nt], 0, 0, 0);
      }
    }

    const bool need_mask = (kv0 + 64 > wq0);  // wave-uniform
#pragma unroll
    for (int mi = 0; mi < 2; ++mi) {
#pragma unroll
      for (int r = 0; r < 4; ++r) {
        const int qg = wq0 + mi * 16 + quad * 4 + r;
        float acc = 0.0f;
#pragma unroll
        for (int nt = 0; nt < 4; ++nt) {
          float e = exp2f(s[mi][nt][r] * 0.0112718764f);  // (1/128)*log2(e)
          if (need_mask && (kv0 + nt * 16 + r16 > qg)) e = 0.0f;
          acc += e;
          pl[(mi * 16 + quad * 4 + r) * 72 + nt * 16 + r16] = f2bf(e);
        }
        rs_l[mi][r] += acc;
      }
    }

    // O += P V  (A-frag from Ps, B-frag: vT[d=n][kv=k] swizzled from Vs)
#pragma unroll
    for (int kc = 0; kc < 2; ++kc) {
      bf16x8 ap[2];
#pragma unroll
      for (int mi = 0; mi < 2; ++mi)
        ap[mi] = __builtin_bit_cast(bf16x8,
            *(const u32x4*)(pl + (mi * 16 + r16) * 72 + kc * 32 + quad * 8));
#pragma unroll
      for (int d = 0; d < 8; ++d) {
        const int drow = d * 16 + r16;
        const int chunk = kc * 4 + quad;
        bf16x8 bv = __builtin_bit_cast(bf16x8,
            *(const u32x4*)(Vs + (drow * 8 + (chunk ^ (drow & 7))) * 8));
#pragma unroll
        for (int mi = 0; mi < 2; ++mi)
          o[mi][d] = __builtin_amdgcn_mfma_f32_16x16x32_bf16(ap[mi], bv, o[mi][d], 0, 0, 0);
      }
    }
    // no trailing sync: next iteration's first barrier separates reads from writes
  }

  // finalize: one l-reduction at the end, then normalize + store
#pragma unroll
  for (int mi = 0; mi < 2; ++mi) {
#pragma unroll
    for (int r = 0; r < 4; ++r) {
      float rs = rs_l[mi][r];
#pragma unroll
      for (int off = 8; off >= 1; off >>= 1) rs += __shfl_xor(rs, off);
      const float inv = 1.0f / rs;
      const int qg = wq0 + mi * 16 + quad * 4 + r;
      unsigned short* yp = y + (size_t)(b * 2048 + qg) * 2048 + h * 128;
#pragma unroll
      for (int d = 0; d < 8; ++d)
        yp[d * 16 + r16] = f2bf(o[mi][d][r] * inv);
    }
  }
#undef ATTN_LOADREGS
}

extern "C" void kernel_launch(void* const* d_in, const int* in_sizes, int n_in,
                              void* d_out, int out_size, void* d_ws, size_t ws_size,
                              hipStream_t stream) {
  const float* x     = (const float*)d_in[0];
  const float* W_qkv = (const float*)d_in[1];
  const float* b_qkv = (const float*)d_in[2];
  const float* W_out = (const float*)d_in[3];
  const float* b_out = (const float*)d_in[4];

  unsigned short* ws  = (unsigned short*)d_ws;
  unsigned short* qkv = ws;                   // 50,331,648
  unsigned short* vT  = ws + 50331648;        // 16,777,216
  unsigned short* xb  = ws + 67108864;        // 16,777,216 (y overlays xb)
  unsigned short* wqT = ws + 83886080;        // 12,582,912
  unsigned short* woT = ws + 96468992;        //  4,194,304
  unsigned short* y   = xb;

  cast_x_kernel<<<8192, 256, 0, stream>>>(x, xb);
  transpose_cast_w<<<dim3(32, 96), 256, 0, stream>>>(W_qkv, wqT, 2048, 6144);
  transpose_cast_w<<<dim3(32, 32), 256, 0, stream>>>(W_out, woT, 2048, 2048);
  gemm_bt<true><<<dim3(32, 24), 512, 0, stream>>>(xb, wqT, b_qkv, qkv, 8192, 6144, 2048);
  transpose_v_kernel<<<dim3(32, 2, 64), 256, 0, stream>>>(qkv, vT);
  attn_kernel<<<dim3(64, 16), 256, 0, stream>>>(qkv, vT, y);
  gemm_bt<false><<<dim3(32, 8), 512, 0, stream>>>(y, woT, b_out, d_out, 8192, 2048, 2048);
}

// Round 6
// 574.447 us; speedup vs baseline: 1.3373x; 1.3373x over previous
//
#include <hip/hip_runtime.h>
#include <hip/hip_bf16.h>
#include <cstdint>

// MupCausalSelfAttention on MI355X (gfx950), bf16 MFMA pipeline.
// B=4, T=2048, C=2048, H=16, Dh=128. muP scale = 1/Dh = 1/128.
//
// ws layout (bf16 elems):
//   qkv  : [8192][6144]                 50,331,648 elems
//   vT   : [64 bh][128 d][2048 t]       16,777,216
//   xb/y : [8192][2048] (y overlays xb) 16,777,216
//   wqT  : [6144][2048]                 12,582,912
//   woT  : [2048][2048]                  4,194,304
//   total 100,663,296 elems = 201,326,592 bytes of d_ws.

using f32x4  = __attribute__((ext_vector_type(4))) float;
using u32x4  = __attribute__((ext_vector_type(4))) unsigned int;
using u16x8  = __attribute__((ext_vector_type(8))) unsigned short;
using u16x4  = __attribute__((ext_vector_type(4))) unsigned short;
using bf16x8 = __attribute__((ext_vector_type(8))) __bf16;

__device__ __forceinline__ unsigned short f2bf(float f) {
  unsigned int u = __builtin_bit_cast(unsigned int, f);
  u += 0x7fffu + ((u >> 16) & 1u);   // round-to-nearest-even
  return (unsigned short)(u >> 16);
}

// async 16B global->LDS DMA (dest is wave-uniform base + lane*16)
__device__ __forceinline__ void async_copy16(const unsigned short* g, unsigned short* l) {
  __builtin_amdgcn_global_load_lds(
      (const __attribute__((address_space(1))) unsigned int*)g,
      (__attribute__((address_space(3))) unsigned int*)l,
      16, 0, 0);
}

// ---------------- cast x fp32 -> bf16, 8 elems/thread ----------------
__global__ __launch_bounds__(256) void cast_x_kernel(const float* __restrict__ x,
                                                     unsigned short* __restrict__ xb) {
  const size_t i = (size_t)blockIdx.x * 256 + threadIdx.x;
  const float* p = x + i * 8;
  f32x4 a = *(const f32x4*)p;
  f32x4 b = *(const f32x4*)(p + 4);
  u16x8 o;
#pragma unroll
  for (int e = 0; e < 4; ++e) { o[e] = f2bf(a[e]); o[e + 4] = f2bf(b[e]); }
  *(u32x4*)(xb + i * 8) = __builtin_bit_cast(u32x4, o);
}

// ---------- W[K][N] fp32 -> WT[N][K] bf16, 64x64 LDS tile ----------
__global__ __launch_bounds__(256) void transpose_cast_w(const float* __restrict__ W,
                                                        unsigned short* __restrict__ WT,
                                                        int K, int N) {
  __shared__ unsigned short tbuf[64 * 68];
  const int tid = threadIdx.x;
  const int k0 = blockIdx.x * 64, n0 = blockIdx.y * 64;
#pragma unroll
  for (int it = 0; it < 4; ++it) {
    int c = it * 256 + tid;
    int kl = c >> 4, n4 = (c & 15) * 4;
    f32x4 v = *(const f32x4*)(W + (size_t)(k0 + kl) * N + n0 + n4);
#pragma unroll
    for (int e = 0; e < 4; ++e) tbuf[(n4 + e) * 68 + kl] = f2bf(v[e]);
  }
  __syncthreads();
#pragma unroll
  for (int it = 0; it < 2; ++it) {
    int c = it * 256 + tid;
    int nl = c >> 3, k8 = (c & 7) * 8;
    u16x4 lo = *(const u16x4*)&tbuf[nl * 68 + k8];
    u16x4 hi = *(const u16x4*)&tbuf[nl * 68 + k8 + 4];
    u16x8 o;
#pragma unroll
    for (int e = 0; e < 4; ++e) { o[e] = lo[e]; o[e + 4] = hi[e]; }
    *(u32x4*)(WT + (size_t)(n0 + nl) * K + k0 + k8) = __builtin_bit_cast(u32x4, o);
  }
}

// ---- qkv V-slice -> vT[bh][128 d][2048 t] bf16, 64x64 LDS tile ----
__global__ __launch_bounds__(256) void transpose_v_kernel(const unsigned short* __restrict__ qkv,
                                                          unsigned short* __restrict__ vT) {
  __shared__ unsigned short tbuf[64 * 68];
  const int tid = threadIdx.x;
  const int t0 = blockIdx.x * 64;
  const int d0 = blockIdx.y * 64;
  const int bh = blockIdx.z;
  const int b = bh >> 4, h = bh & 15;
#pragma unroll
  for (int it = 0; it < 2; ++it) {
    int c = it * 256 + tid;
    int tl = c >> 3, d8 = (c & 7) * 8;
    u32x4 v = *(const u32x4*)(qkv + (size_t)(b * 2048 + t0 + tl) * 6144 + 4096 + h * 128 + d0 + d8);
    u16x8 u = __builtin_bit_cast(u16x8, v);
#pragma unroll
    for (int e = 0; e < 8; ++e) tbuf[(d8 + e) * 68 + tl] = u[e];
  }
  __syncthreads();
#pragma unroll
  for (int it = 0; it < 2; ++it) {
    int c = it * 256 + tid;
    int dl = c >> 3, t8 = (c & 7) * 8;
    u16x4 lo = *(const u16x4*)&tbuf[dl * 68 + t8];
    u16x4 hi = *(const u16x4*)&tbuf[dl * 68 + t8 + 4];
    u16x8 o;
#pragma unroll
    for (int e = 0; e < 4; ++e) { o[e] = lo[e]; o[e + 4] = hi[e]; }
    *(u32x4*)(vT + ((size_t)bh * 128 + d0 + dl) * 2048 + t0 + t8) = __builtin_bit_cast(u32x4, o);
  }
}

// ================== 256x256 8-phase GEMM (m201 geometry) ==================
// C[M,N] = A[M,K] @ BT[N,K]^T + bias. bf16 MFMA 16x16x32, BK=64.
// 512 threads = 8 waves (2M x 4N), per-wave C = 128x64.
// LDS per operand: [2 buf][2 row-half][128 rows][64 k] bf16 = 64KB; 128KB total.
// Row layout: 128B/row = 8 chunks of 16B; swizzle chunk c ^= (row&7) on BOTH
// staging source and fragment read (involution; 2 lanes/bank-group = free).
// Tile t lives in buf t&1. Tile t+2 overwrites the SAME buf region-by-region
// after each region's last read: B-halves (last read P2) staged at P3,
// A-halves (last read P3) staged at P4. ONE wait per K-tile: vmcnt(8) at
// P4-end. Issue-to-wait distance ~4-5 phases.

// stage one 16KB region (128 rows x 64 k bf16): 2 global_load_lds/thread
__device__ __forceinline__ void stage_region(const unsigned short* gsrc, int K,
                                             unsigned short* region, int tid) {
#pragma unroll
  for (int l = 0; l < 2; ++l) {
    const int s = l * 512 + tid;          // 0..1023 slots of 16B
    const int row = s >> 3, c = s & 7;
    const int g = c ^ (row & 7);
    async_copy16(gsrc + (size_t)row * K + g * 8, region + s * 8);
  }
}

__device__ __forceinline__ bf16x8 lds_frag(const unsigned short* region, int row, int ch) {
  return __builtin_bit_cast(bf16x8,
      *(const u32x4*)(region + row * 64 + ((ch ^ (row & 7)) * 8)));
}

template <bool OUT_BF16>
__global__ __launch_bounds__(512, 1) void gemm_bt(const unsigned short* __restrict__ A,
                                                  const unsigned short* __restrict__ BT,
                                                  const float* __restrict__ bias,
                                                  void* __restrict__ Cout,
                                                  int M, int N, int K) {
  __shared__ unsigned short As[32768];   // [buf][rh][128*64]
  __shared__ unsigned short Bs[32768];

  const int tid  = threadIdx.x;
  const int lane = tid & 63;
  const int wave = tid >> 6;
  const int r16  = lane & 15;
  const int quad = lane >> 4;
  const int wm   = (wave >> 2) * 128;
  const int wn   = (wave & 3) * 64;
  const int rhA  = wave >> 2;          // wave's A row-half
  const int rhB  = (wave >> 1) & 1;    // wave's B row-half
  const int brow = wn & 64;            // wave's base row within its B region

  // XCD-aware mapping: XCD x owns m-chunk [x*MC, x*MC+MC) x all n (n-major walk).
  const int orig = blockIdx.y * gridDim.x + blockIdx.x;
  const int xcd  = orig & 7;
  const int kb   = orig >> 3;
  const int MC   = gridDim.x >> 3;
  const int m0   = (xcd * MC + (kb % MC)) * 256;
  const int n0   = (kb / MC) * 256;

  const unsigned short* Ag = A + (size_t)m0 * K;
  const unsigned short* Bg = BT + (size_t)n0 * K;
  const int NT = K >> 6;

  f32x4 acc[8][4] = {};

  // prologue: stage tiles 0 and 1 in steady-state region order (B0,B1,A0,A1)
#pragma unroll
  for (int tt = 0; tt < 2; ++tt) {
    const size_t kk0 = (size_t)tt * 64;
    unsigned short* Ad = As + tt * 16384;
    unsigned short* Bd = Bs + tt * 16384;
    stage_region(Bg + kk0, K, Bd, tid);
    stage_region(Bg + (size_t)128 * K + kk0, K, Bd + 8192, tid);
    stage_region(Ag + kk0, K, Ad, tid);
    stage_region(Ag + (size_t)128 * K + kk0, K, Ad + 8192, tid);
  }
  asm volatile("s_waitcnt vmcnt(8)" ::: "memory");   // tile 0 landed; tile 1 in flight
  __builtin_amdgcn_s_barrier();

  for (int t = 0; t < NT; ++t) {
    const int buf = t & 1;
    const unsigned short* Ar = As + buf * 16384 + rhA * 8192;
    const unsigned short* Br = Bs + buf * 16384 + rhB * 8192;
    unsigned short* Asg = As + buf * 16384;   // tile t+2 overwrites current buf
    unsigned short* Bsg = Bs + buf * 16384;
    const bool pre = (t + 2 < NT);
    const size_t kpre = (size_t)(t + 2) << 6;

    bf16x8 a0[4][2], a1[4][2], b0[2][2], b1[2][2];

    // ---------------- P1: read A[mq0] + B[nq0]; MFMA acc[0-3][0-1] ----------------
#pragma unroll
    for (int mi = 0; mi < 4; ++mi)
#pragma unroll
      for (int kk = 0; kk < 2; ++kk)
        a0[mi][kk] = lds_frag(Ar, mi * 16 + r16, kk * 4 + quad);
#pragma unroll
    for (int nj = 0; nj < 2; ++nj)
#pragma unroll
      for (int kk = 0; kk < 2; ++kk)
        b0[nj][kk] = lds_frag(Br, brow + nj * 16 + r16, kk * 4 + quad);
    __builtin_amdgcn_s_barrier();
    asm volatile("s_waitcnt lgkmcnt(0)" ::: "memory");
    __builtin_amdgcn_sched_barrier(0);
    __builtin_amdgcn_s_setprio(1);
#pragma unroll
    for (int mi = 0; mi < 4; ++mi)
#pragma unroll
      for (int nj = 0; nj < 2; ++nj)
#pragma unroll
        for (int kk = 0; kk < 2; ++kk)
          acc[mi][nj] = __builtin_amdgcn_mfma_f32_16x16x32_bf16(a0[mi][kk], b0[nj][kk], acc[mi][nj], 0, 0, 0);
    __builtin_amdgcn_s_setprio(0);
    __builtin_amdgcn_s_barrier();

    // ---------------- P2: read B[nq1]; MFMA acc[0-3][2-3] ----------------
#pragma unroll
    for (int nj = 0; nj < 2; ++nj)
#pragma unroll
      for (int kk = 0; kk < 2; ++kk)
        b1[nj][kk] = lds_frag(Br, brow + 32 + nj * 16 + r16, kk * 4 + quad);
    __builtin_amdgcn_s_barrier();
    asm volatile("s_waitcnt lgkmcnt(0)" ::: "memory");
    __builtin_amdgcn_sched_barrier(0);
    __builtin_amdgcn_s_setprio(1);
#pragma unroll
    for (int mi = 0; mi < 4; ++mi)
#pragma unroll
      for (int nj = 0; nj < 2; ++nj)
#pragma unroll
        for (int kk = 0; kk < 2; ++kk)
          acc[mi][nj + 2] = __builtin_amdgcn_mfma_f32_16x16x32_bf16(a0[mi][kk], b1[nj][kk], acc[mi][nj + 2], 0, 0, 0);
    __builtin_amdgcn_s_setprio(0);
    __builtin_amdgcn_s_barrier();

    // ------- P3: read A[mq1]; stage B(t+2) both halves; MFMA acc[4-7][2-3] -------
#pragma unroll
    for (int mi = 0; mi < 4; ++mi)
#pragma unroll
      for (int kk = 0; kk < 2; ++kk)
        a1[mi][kk] = lds_frag(Ar, 64 + mi * 16 + r16, kk * 4 + quad);
    if (pre) {
      stage_region(Bg + kpre, K, Bsg, tid);
      stage_region(Bg + (size_t)128 * K + kpre, K, Bsg + 8192, tid);
    }
    __builtin_amdgcn_s_barrier();
    asm volatile("s_waitcnt lgkmcnt(0)" ::: "memory");
    __builtin_amdgcn_sched_barrier(0);
    __builtin_amdgcn_s_setprio(1);
#pragma unroll
    for (int mi = 0; mi < 4; ++mi)
#pragma unroll
      for (int nj = 0; nj < 2; ++nj)
#pragma unroll
        for (int kk = 0; kk < 2; ++kk)
          acc[mi + 4][nj + 2] = __builtin_amdgcn_mfma_f32_16x16x32_bf16(a1[mi][kk], b1[nj][kk], acc[mi + 4][nj + 2], 0, 0, 0);
    __builtin_amdgcn_s_setprio(0);
    __builtin_amdgcn_s_barrier();

    // ------- P4: stage A(t+2) both halves; MFMA acc[4-7][0-1]; vmcnt(8) -------
    if (pre) {
      stage_region(Ag + kpre, K, Asg, tid);
      stage_region(Ag + (size_t)128 * K + kpre, K, Asg + 8192, tid);
    }
    __builtin_amdgcn_s_barrier();
    __builtin_amdgcn_sched_barrier(0);
    __builtin_amdgcn_s_setprio(1);
#pragma unroll
    for (int mi = 0; mi < 4; ++mi)
#pragma unroll
      for (int nj = 0; nj < 2; ++nj)
#pragma unroll
        for (int kk = 0; kk < 2; ++kk)
          acc[mi + 4][nj] = __builtin_amdgcn_mfma_f32_16x16x32_bf16(a1[mi][kk], b0[nj][kk], acc[mi + 4][nj], 0, 0, 0);
    __builtin_amdgcn_s_setprio(0);
    if (pre) { asm volatile("s_waitcnt vmcnt(8)" ::: "memory"); }  // t+1 landed; t+2 flying
    else     { asm volatile("s_waitcnt vmcnt(0)" ::: "memory"); }
    __builtin_amdgcn_s_barrier();
  }

  // epilogue
#pragma unroll
  for (int nj = 0; nj < 4; ++nj) {
    const int n = n0 + wn + nj * 16 + r16;
    const float bv = bias[n];
#pragma unroll
    for (int mi = 0; mi < 8; ++mi) {
      const int mr = m0 + wm + mi * 16 + quad * 4;
#pragma unroll
      for (int r = 0; r < 4; ++r) {
        float v = acc[mi][nj][r] + bv;
        if constexpr (OUT_BF16)
          ((unsigned short*)Cout)[(size_t)(mr + r) * N + n] = f2bf(v);
        else
          ((float*)Cout)[(size_t)(mr + r) * N + n] = v;
      }
    }
  }
}

// --------------- flash attention v2, causal, muP scale 1/128 ---------------
// Block = 4 waves, 128 q-rows (32/wave as 2 m-tiles). kv tiles of 64.
// T14 async-STAGE: K/V tile t+1 loaded global->reg BEFORE computing tile t
// (issue-to-use distance = one compute phase >> HBM latency), then after the
// end-of-compute barrier: vmcnt(0) (free) -> ds_write -> lgkmcnt(0) -> issue
// loads t+2 -> barrier -> compute. Raw barriers; no vmcnt(0)-drain per tile.
// Grid (64 bh, 16 y): qt = 15-y so heavy blocks dispatch FIRST (no late tail);
// orig&7 = bh&7 so a head's K/V stays on one XCD's L2.
// __launch_bounds__(256,2): VGPR cap 256 >> ~200 live set. Round-5's (256,3)
// capped at 170 -> scratch spill (WRITE_SIZE 563MB/dispatch, VGPR 84) -> 330us.
// No online max: muP scale 1/128 keeps logits O(1); softmax shift-invariant.
__global__ __launch_bounds__(256, 2) void attn_kernel(const unsigned short* __restrict__ qkv,
                                                      const unsigned short* __restrict__ vT,
                                                      unsigned short* __restrict__ y) {
  __shared__ unsigned short Ks[64 * 128];    // [kvrow][chunk c]: holds K chunk c^(row&15)
  __shared__ unsigned short Vs[128 * 64];    // [drow][chunk c]: holds vT chunk c^(drow&7)
  __shared__ unsigned short Ps[4][32 * 72];  // per-wave P (C-layout -> A-layout bridge)

  const int tid  = threadIdx.x;
  const int lane = tid & 63;
  const int wave = tid >> 6;
  const int r16  = lane & 15;
  const int quad = lane >> 4;
  const int qt   = 15 - blockIdx.y;          // heavy (large-q) blocks dispatch first
  const int q0   = qt * 128;
  const int bh   = blockIdx.x;               // XCD = bh&7 -> per-head L2 locality
  const int b    = bh >> 4, h = bh & 15;
  const int wq0  = q0 + wave * 32;
  unsigned short* pl = Ps[wave];

  // Q A-frags: Q[m=r16][k=kc*32+quad*8+j]
  bf16x8 aq[2][4];
#pragma unroll
  for (int mi = 0; mi < 2; ++mi) {
    const unsigned short* qp = qkv + (size_t)(b * 2048 + wq0 + mi * 16 + r16) * 6144 + h * 128;
#pragma unroll
    for (int kc = 0; kc < 4; ++kc)
      aq[mi][kc] = __builtin_bit_cast(bf16x8, *(const u32x4*)(qp + kc * 32 + quad * 8));
  }

  f32x4 o[2][8] = {};
  float rs_l[2][4] = {};

  const unsigned short* kbase = qkv + (size_t)b * 2048 * 6144 + 2048 + h * 128;
  const unsigned short* vbase = vT + (size_t)bh * 128 * 2048;
  const int ntiles = 2 * qt + 2;

  // staging geometry (swizzle applied on the GLOBAL side; LDS dest linear):
  // K: slot=it*256+tid -> row=it*16+(tid>>4), src chunk kg=(tid&15)^(tid>>4)
  // V: slot=it*256+tid -> dr=it*32+(tid>>3), src chunk vg=(tid&7)^((tid>>3)&7)
  const int kg = (tid & 15) ^ (tid >> 4);
  const int vg = (tid & 7) ^ ((tid >> 3) & 7);
  const int krow0 = tid >> 4;
  const int vrow0 = tid >> 3;

  u32x4 kreg[4], vreg[4];

#define ATTN_LOADREGS(KV0)                                                              \
  {                                                                                     \
    _Pragma("unroll")                                                                   \
    for (int it = 0; it < 4; ++it)                                                      \
      kreg[it] = *(const u32x4*)(kbase + (size_t)((KV0) + it * 16 + krow0) * 6144 + kg * 8); \
    _Pragma("unroll")                                                                   \
    for (int it = 0; it < 4; ++it)                                                      \
      vreg[it] = *(const u32x4*)(vbase + (size_t)(it * 32 + vrow0) * 2048 + (KV0) + vg * 8); \
  }

  ATTN_LOADREGS(0);

  for (int t = 0; t < ntiles; ++t) {
    const int kv0 = t * 64;
    // ---- stage phase: regs (loaded one compute-phase ago) -> LDS ----
    asm volatile("s_waitcnt vmcnt(0)" ::: "memory");   // near-free: issued ~1 tile ago
    __builtin_amdgcn_s_barrier();                      // prev compute done reading LDS
    __builtin_amdgcn_sched_barrier(0);
#pragma unroll
    for (int it = 0; it < 4; ++it)
      *(u32x4*)(Ks + (it * 256 + tid) * 8) = kreg[it];
#pragma unroll
    for (int it = 0; it < 4; ++it)
      *(u32x4*)(Vs + (it * 256 + tid) * 8) = vreg[it];
    asm volatile("s_waitcnt lgkmcnt(0)" ::: "memory"); // writes done; regs reusable
    if (t + 1 < ntiles) ATTN_LOADREGS(kv0 + 64);       // prefetch next tile
    __builtin_amdgcn_s_barrier();                      // all waves' writes visible
    __builtin_amdgcn_sched_barrier(0);

    // S = Q K^T  (B-frag: K[kv=n][d=k], swizzled read from Ks)
    f32x4 s[2][4] = {};
#pragma unroll
    for (int kc = 0; kc < 4; ++kc) {
#pragma unroll
      for (int nt = 0; nt < 4; ++nt) {
        const int krow = nt * 16 + r16;
        const int chunk = kc * 4 + quad;
        bf16x8 bk = __builtin_bit_cast(bf16x8,
            *(const u32x4*)(Ks + (krow * 16 + (chunk ^ (krow & 15))) * 8));
#pragma unroll
        for (int mi = 0; mi < 2; ++mi)
          s[mi][nt] = __builtin_amdgcn_mfma_f32_16x16x32_bf16(aq[mi][kc], bk, s[mi][nt], 0, 0, 0);
      }
    }

    const bool need_mask = (kv0 + 64 > wq0);  // wave-uniform
#pragma unroll
    for (int mi = 0; mi < 2; ++mi) {
#pragma unroll
      for (int r = 0; r < 4; ++r) {
        const int qg = wq0 + mi * 16 + quad * 4 + r;
        float acc = 0.0f;
#pragma unroll
        for (int nt = 0; nt < 4; ++nt) {
          float e = exp2f(s[mi][nt][r] * 0.0112718764f);  // (1/128)*log2(e)
          if (need_mask && (kv0 + nt * 16 + r16 > qg)) e = 0.0f;
          acc += e;
          pl[(mi * 16 + quad * 4 + r) * 72 + nt * 16 + r16] = f2bf(e);
        }
        rs_l[mi][r] += acc;
      }
    }

    // O += P V  (A-frag from Ps, B-frag: vT[d=n][kv=k] swizzled from Vs)
#pragma unroll
    for (int kc = 0; kc < 2; ++kc) {
      bf16x8 ap[2];
#pragma unroll
      for (int mi = 0; mi < 2; ++mi)
        ap[mi] = __builtin_bit_cast(bf16x8,
            *(const u32x4*)(pl + (mi * 16 + r16) * 72 + kc * 32 + quad * 8));
#pragma unroll
      for (int d = 0; d < 8; ++d) {
        const int drow = d * 16 + r16;
        const int chunk = kc * 4 + quad;
        bf16x8 bv = __builtin_bit_cast(bf16x8,
            *(const u32x4*)(Vs + (drow * 8 + (chunk ^ (drow & 7))) * 8));
#pragma unroll
        for (int mi = 0; mi < 2; ++mi)
          o[mi][d] = __builtin_amdgcn_mfma_f32_16x16x32_bf16(ap[mi], bv, o[mi][d], 0, 0, 0);
      }
    }
    // no trailing sync: next iteration's first barrier separates reads from writes
  }

  // finalize: one l-reduction at the end, then normalize + store
#pragma unroll
  for (int mi = 0; mi < 2; ++mi) {
#pragma unroll
    for (int r = 0; r < 4; ++r) {
      float rs = rs_l[mi][r];
#pragma unroll
      for (int off = 8; off >= 1; off >>= 1) rs += __shfl_xor(rs, off);
      const float inv = 1.0f / rs;
      const int qg = wq0 + mi * 16 + quad * 4 + r;
      unsigned short* yp = y + (size_t)(b * 2048 + qg) * 2048 + h * 128;
#pragma unroll
      for (int d = 0; d < 8; ++d)
        yp[d * 16 + r16] = f2bf(o[mi][d][r] * inv);
    }
  }
#undef ATTN_LOADREGS
}

extern "C" void kernel_launch(void* const* d_in, const int* in_sizes, int n_in,
                              void* d_out, int out_size, void* d_ws, size_t ws_size,
                              hipStream_t stream) {
  const float* x     = (const float*)d_in[0];
  const float* W_qkv = (const float*)d_in[1];
  const float* b_qkv = (const float*)d_in[2];
  const float* W_out = (const float*)d_in[3];
  const float* b_out = (const float*)d_in[4];

  unsigned short* ws  = (unsigned short*)d_ws;
  unsigned short* qkv = ws;                   // 50,331,648
  unsigned short* vT  = ws + 50331648;        // 16,777,216
  unsigned short* xb  = ws + 67108864;        // 16,777,216 (y overlays xb)
  unsigned short* wqT = ws + 83886080;        // 12,582,912
  unsigned short* woT = ws + 96468992;        //  4,194,304
  unsigned short* y   = xb;

  cast_x_kernel<<<8192, 256, 0, stream>>>(x, xb);
  transpose_cast_w<<<dim3(32, 96), 256, 0, stream>>>(W_qkv, wqT, 2048, 6144);
  transpose_cast_w<<<dim3(32, 32), 256, 0, stream>>>(W_out, woT, 2048, 2048);
  gemm_bt<true><<<dim3(32, 24), 512, 0, stream>>>(xb, wqT, b_qkv, qkv, 8192, 6144, 2048);
  transpose_v_kernel<<<dim3(32, 2, 64), 256, 0, stream>>>(qkv, vT);
  attn_kernel<<<dim3(64, 16), 256, 0, stream>>>(qkv, vT, y);
  gemm_bt<false><<<dim3(32, 8), 512, 0, stream>>>(y, woT, b_out, d_out, 8192, 2048, 2048);
}